// Round 1
// baseline (2032.249 us; speedup 1.0000x reference)
//
#include <hip/hip_runtime.h>
#include <math.h>

#define HID 1024
#define NH 16
#define HD 64
#define NB 8
#define SEQ 1024
#define MTOK (NB * SEQ)   // 8192 token rows

// ---------------------------------------------------------------------------
// C[M,N] = A[M,K] * W[N,K]^T + bias
// LAYOUT 0: C row-major [M,N];  LAYOUT 1: head-split [B,H,S,HD]
// 128x128 block tile, BK=16, 256 threads, 8x8 microtile.
// ---------------------------------------------------------------------------
template <int LAYOUT>
__global__ __launch_bounds__(256) void gemm_nt_bias_k(
    const float* __restrict__ A, const float* __restrict__ W,
    const float* __restrict__ bias, float* __restrict__ C,
    int M, int N, int K) {
  __shared__ float As[16][132];   // [k][m], pad 132: 528B row = 33*16B (keeps 16B align, <=2-way banks)
  __shared__ float Ws[16][132];   // [k][n]
  const int tid = threadIdx.x;
  const int row0 = blockIdx.y * 128;
  const int col0 = blockIdx.x * 128;
  const int tx = tid & 15, ty = tid >> 4;
  const int m0 = ty * 8, n0 = tx * 8;
  float acc[8][8];
#pragma unroll
  for (int i = 0; i < 8; ++i)
#pragma unroll
    for (int j = 0; j < 8; ++j) acc[i][j] = 0.f;

  for (int kt = 0; kt < K; kt += 16) {
#pragma unroll
    for (int l = 0; l < 2; ++l) {
      const int idx = tid + l * 256;       // 0..511 -> 128 rows x 4 float4
      const int m = idx >> 2, k4 = idx & 3;
      const float4 av = *(const float4*)(A + (size_t)(row0 + m) * K + kt + k4 * 4);
      As[k4 * 4 + 0][m] = av.x; As[k4 * 4 + 1][m] = av.y;
      As[k4 * 4 + 2][m] = av.z; As[k4 * 4 + 3][m] = av.w;
      const float4 wv = *(const float4*)(W + (size_t)(col0 + m) * K + kt + k4 * 4);
      Ws[k4 * 4 + 0][m] = wv.x; Ws[k4 * 4 + 1][m] = wv.y;
      Ws[k4 * 4 + 2][m] = wv.z; Ws[k4 * 4 + 3][m] = wv.w;
    }
    __syncthreads();
#pragma unroll
    for (int k = 0; k < 16; ++k) {
      float a[8], b[8];
      *(float4*)&a[0] = *(const float4*)&As[k][m0];
      *(float4*)&a[4] = *(const float4*)&As[k][m0 + 4];
      *(float4*)&b[0] = *(const float4*)&Ws[k][n0];
      *(float4*)&b[4] = *(const float4*)&Ws[k][n0 + 4];
#pragma unroll
      for (int i = 0; i < 8; ++i)
#pragma unroll
        for (int j = 0; j < 8; ++j) acc[i][j] = fmaf(a[i], b[j], acc[i][j]);
    }
    __syncthreads();
  }

#pragma unroll
  for (int i = 0; i < 8; ++i) {
    const int n = row0 + m0 + i;
#pragma unroll
    for (int j4 = 0; j4 < 2; ++j4) {
      const int j = col0 + n0 + j4 * 4;
      float4 r;
      r.x = acc[i][j4 * 4 + 0] + bias[j + 0];
      r.y = acc[i][j4 * 4 + 1] + bias[j + 1];
      r.z = acc[i][j4 * 4 + 2] + bias[j + 2];
      r.w = acc[i][j4 * 4 + 3] + bias[j + 3];
      if (LAYOUT == 0) {
        *(float4*)(C + (size_t)n * N + j) = r;
      } else {
        const int b_ = n >> 10, s_ = n & 1023;
        const int h_ = j >> 6, hd = j & 63;
        // [B,H,S,HD]; hd is 4-aligned and never crosses a 64 boundary
        *(float4*)(C + ((size_t)(b_ * NH + h_) * SEQ + s_) * HD + hd) = r;
      }
    }
  }
}

// ---------------------------------------------------------------------------
// scores[bh] = q[bh] (1024x64) * k[bh]^T (64x1024) * 0.125  -> attn slab
// ---------------------------------------------------------------------------
__global__ __launch_bounds__(256) void attn_scores_k(
    const float* __restrict__ q, const float* __restrict__ kmat,
    float* __restrict__ attn) {
  __shared__ float As[16][132];
  __shared__ float Bs[16][132];
  const int bh = blockIdx.z;
  const float* qp = q + (size_t)bh * SEQ * HD;
  const float* kp = kmat + (size_t)bh * SEQ * HD;
  float* op = attn + (size_t)bh * SEQ * SEQ;
  const int tid = threadIdx.x;
  const int row0 = blockIdx.y * 128;
  const int col0 = blockIdx.x * 128;
  const int tx = tid & 15, ty = tid >> 4;
  const int m0 = ty * 8, n0 = tx * 8;
  float acc[8][8];
#pragma unroll
  for (int i = 0; i < 8; ++i)
#pragma unroll
    for (int j = 0; j < 8; ++j) acc[i][j] = 0.f;

  for (int kt = 0; kt < HD; kt += 16) {
#pragma unroll
    for (int l = 0; l < 2; ++l) {
      const int idx = tid + l * 256;
      const int m = idx >> 2, k4 = idx & 3;
      const float4 av = *(const float4*)(qp + (size_t)(row0 + m) * HD + kt + k4 * 4);
      As[k4 * 4 + 0][m] = av.x; As[k4 * 4 + 1][m] = av.y;
      As[k4 * 4 + 2][m] = av.z; As[k4 * 4 + 3][m] = av.w;
      const float4 bv = *(const float4*)(kp + (size_t)(col0 + m) * HD + kt + k4 * 4);
      Bs[k4 * 4 + 0][m] = bv.x; Bs[k4 * 4 + 1][m] = bv.y;
      Bs[k4 * 4 + 2][m] = bv.z; Bs[k4 * 4 + 3][m] = bv.w;
    }
    __syncthreads();
#pragma unroll
    for (int k = 0; k < 16; ++k) {
      float a[8], b[8];
      *(float4*)&a[0] = *(const float4*)&As[k][m0];
      *(float4*)&a[4] = *(const float4*)&As[k][m0 + 4];
      *(float4*)&b[0] = *(const float4*)&Bs[k][n0];
      *(float4*)&b[4] = *(const float4*)&Bs[k][n0 + 4];
#pragma unroll
      for (int i = 0; i < 8; ++i)
#pragma unroll
        for (int j = 0; j < 8; ++j) acc[i][j] = fmaf(a[i], b[j], acc[i][j]);
    }
    __syncthreads();
  }

#pragma unroll
  for (int i = 0; i < 8; ++i) {
    const int n = row0 + m0 + i;
#pragma unroll
    for (int j4 = 0; j4 < 2; ++j4) {
      const int j = col0 + n0 + j4 * 4;
      float4 r;
      r.x = acc[i][j4 * 4 + 0] * 0.125f;
      r.y = acc[i][j4 * 4 + 1] * 0.125f;
      r.z = acc[i][j4 * 4 + 2] * 0.125f;
      r.w = acc[i][j4 * 4 + 3] * 0.125f;
      *(float4*)(op + (size_t)n * SEQ + j) = r;
    }
  }
}

// ---------------------------------------------------------------------------
// In-place row softmax over last dim (1024). One 256-thread block per row.
// ---------------------------------------------------------------------------
__global__ __launch_bounds__(256) void softmax_k(float* __restrict__ attn) {
  __shared__ float smax[4], ssum[4];
  float* p = attn + (size_t)blockIdx.x * SEQ;
  const int tid = threadIdx.x;
  const int lane = tid & 63, wid = tid >> 6;
  float4 v = *(const float4*)(p + tid * 4);

  float m4 = fmaxf(fmaxf(v.x, v.y), fmaxf(v.z, v.w));
#pragma unroll
  for (int o = 32; o > 0; o >>= 1) m4 = fmaxf(m4, __shfl_down(m4, o));
  if (lane == 0) smax[wid] = m4;
  __syncthreads();
  const float rmax = fmaxf(fmaxf(smax[0], smax[1]), fmaxf(smax[2], smax[3]));

  v.x = __expf(v.x - rmax);
  v.y = __expf(v.y - rmax);
  v.z = __expf(v.z - rmax);
  v.w = __expf(v.w - rmax);
  float s4 = v.x + v.y + v.z + v.w;
#pragma unroll
  for (int o = 32; o > 0; o >>= 1) s4 += __shfl_down(s4, o);
  if (lane == 0) ssum[wid] = s4;
  __syncthreads();
  const float rs = 1.f / (ssum[0] + ssum[1] + ssum[2] + ssum[3]);

  v.x *= rs; v.y *= rs; v.z *= rs; v.w *= rs;
  *(float4*)(p + tid * 4) = v;
}

// ---------------------------------------------------------------------------
// ctx: per (b,h): attn[bh] (1024x1024) * v[bh] (1024x64) -> ctx[B,S,HID]
// 128x64 block tile, BK=16, 256 threads, 8x4 microtile.
// ---------------------------------------------------------------------------
__global__ __launch_bounds__(256) void attn_ctx_k(
    const float* __restrict__ attn, const float* __restrict__ v,
    float* __restrict__ ctx) {
  __shared__ float As[16][132];
  __shared__ float Vs[16][68];
  const int bh = blockIdx.z;
  const int b_ = bh >> 4, h_ = bh & 15;
  const float* ap = attn + (size_t)bh * SEQ * SEQ;
  const float* vp = v + (size_t)bh * SEQ * HD;
  const int tid = threadIdx.x;
  const int row0 = blockIdx.y * 128;
  const int tx = tid & 15, ty = tid >> 4;
  const int m0 = ty * 8, n0 = tx * 4;
  float acc[8][4];
#pragma unroll
  for (int i = 0; i < 8; ++i)
#pragma unroll
    for (int j = 0; j < 4; ++j) acc[i][j] = 0.f;

  for (int kt = 0; kt < SEQ; kt += 16) {
#pragma unroll
    for (int l = 0; l < 2; ++l) {
      const int idx = tid + l * 256;
      const int m = idx >> 2, k4 = idx & 3;
      const float4 av = *(const float4*)(ap + (size_t)(row0 + m) * SEQ + kt + k4 * 4);
      As[k4 * 4 + 0][m] = av.x; As[k4 * 4 + 1][m] = av.y;
      As[k4 * 4 + 2][m] = av.z; As[k4 * 4 + 3][m] = av.w;
    }
    {
      const int kk = tid >> 4, n4 = tid & 15;   // 16 rows x 16 float4
      const float4 vv = *(const float4*)(vp + (size_t)(kt + kk) * HD + n4 * 4);
      *(float4*)&Vs[kk][n4 * 4] = vv;
    }
    __syncthreads();
#pragma unroll
    for (int k = 0; k < 16; ++k) {
      float a[8], b[4];
      *(float4*)&a[0] = *(const float4*)&As[k][m0];
      *(float4*)&a[4] = *(const float4*)&As[k][m0 + 4];
      *(float4*)&b[0] = *(const float4*)&Vs[k][n0];
#pragma unroll
      for (int i = 0; i < 8; ++i)
#pragma unroll
        for (int j = 0; j < 4; ++j) acc[i][j] = fmaf(a[i], b[j], acc[i][j]);
    }
    __syncthreads();
  }

#pragma unroll
  for (int i = 0; i < 8; ++i) {
    const int m = row0 + m0 + i;
    float4 r;
    r.x = acc[i][0]; r.y = acc[i][1]; r.z = acc[i][2]; r.w = acc[i][3];
    *(float4*)(ctx + (size_t)(b_ * SEQ + m) * HID + h_ * HD + n0) = r;
  }
}

// ---------------------------------------------------------------------------
extern "C" void kernel_launch(void* const* d_in, const int* in_sizes, int n_in,
                              void* d_out, int out_size, void* d_ws, size_t ws_size,
                              hipStream_t stream) {
  const float* x  = (const float*)d_in[0];
  const float* Wq = (const float*)d_in[1];
  const float* bq = (const float*)d_in[2];
  const float* Wk = (const float*)d_in[3];
  const float* bk = (const float*)d_in[4];
  const float* Wv = (const float*)d_in[5];
  const float* bv = (const float*)d_in[6];
  const float* Wo = (const float*)d_in[7];
  const float* bo = (const float*)d_in[8];

  float* out  = (float*)d_out;                         // [8,1024,1024]
  float* attn = out + (size_t)MTOK * HID;              // [8,16,1024,1024]

  float* ws = (float*)d_ws;
  float* q = ws;                                       // [B,H,S,HD]
  float* k = ws + (size_t)MTOK * HID;
  float* v = ws + 2 * (size_t)MTOK * HID;
  float* ctx = ws;                                     // aliases q (dead after scores)

  const dim3 blk(256);
  const dim3 g1(HID / 128, MTOK / 128);                // (8, 64)
  gemm_nt_bias_k<1><<<g1, blk, 0, stream>>>(x, Wq, bq, q, MTOK, HID, HID);
  gemm_nt_bias_k<1><<<g1, blk, 0, stream>>>(x, Wk, bk, k, MTOK, HID, HID);
  gemm_nt_bias_k<1><<<g1, blk, 0, stream>>>(x, Wv, bv, v, MTOK, HID, HID);

  const dim3 g2(SEQ / 128, SEQ / 128, NB * NH);        // (8, 8, 128)
  attn_scores_k<<<g2, blk, 0, stream>>>(q, k, attn);

  softmax_k<<<dim3(NB * NH * SEQ), blk, 0, stream>>>(attn);

  const dim3 g4(1, SEQ / 128, NB * NH);                // (1, 8, 128)
  attn_ctx_k<<<g4, blk, 0, stream>>>(attn, v, ctx);

  gemm_nt_bias_k<0><<<g1, blk, 0, stream>>>(ctx, Wo, bo, out, MTOK, HID, HID);
}